// Round 6
// baseline (487.759 us; speedup 1.0000x reference)
//
#include <hip/hip_runtime.h>

#define N_NODES 100000
#define IN_CH 16
#define HIDDEN 32
#define NUM_HH 1000

#define NPB 128                                   // nodes per bucket
#define NBUCK ((N_NODES + NPB - 1) / NPB)         // 782
#define NCHUNK 512                                // edge chunks (pass A/B blocks)
#define SCAN_N (NBUCK * NCHUNK)                   // 400384
#define S1_BLOCKS ((SCAN_N + 1023) / 1024)        // 391
#define SORT_CAP 6144                             // bucket mean 4096, std ~64

// ---------------------------------------------------------------------------
// Pass A: per-chunk bucket histogram (LDS), write counts[bucket][chunk].
// ---------------------------------------------------------------------------
__global__ __launch_bounds__(256) void passA_count(const int* __restrict__ dst,
                                                   int* __restrict__ counts,
                                                   int n_edges, int cepb) {
  __shared__ int hist[NBUCK];
  for (int i = threadIdx.x; i < NBUCK; i += 256) hist[i] = 0;
  __syncthreads();
  const int s = blockIdx.x * cepb;
  const int e = min(n_edges, s + cepb);
  for (int i = s + threadIdx.x; i < e; i += 256)
    atomicAdd(&hist[dst[i] >> 7], 1);
  __syncthreads();
  for (int i = threadIdx.x; i < NBUCK; i += 256)
    counts[i * NCHUNK + blockIdx.x] = hist[i];
}

// ---------------------------------------------------------------------------
// Exclusive scan over SCAN_N ints (bucket-major order).
// ---------------------------------------------------------------------------
__global__ __launch_bounds__(1024) void scan_local(const int* __restrict__ in,
                                                   int* __restrict__ out,
                                                   int* __restrict__ partials) {
  __shared__ int tmp[1024];
  const int i = blockIdx.x * 1024 + threadIdx.x;
  const int v = (i < SCAN_N) ? in[i] : 0;
  tmp[threadIdx.x] = v;
  __syncthreads();
  for (int off = 1; off < 1024; off <<= 1) {
    int t = (threadIdx.x >= off) ? tmp[threadIdx.x - off] : 0;
    __syncthreads();
    tmp[threadIdx.x] += t;
    __syncthreads();
  }
  if (i < SCAN_N) out[i] = tmp[threadIdx.x] - v;  // exclusive
  if (threadIdx.x == 1023) partials[blockIdx.x] = tmp[threadIdx.x];
}

__global__ __launch_bounds__(512) void scan_partials(int* __restrict__ partials) {
  __shared__ int tmp[512];
  const int v = (threadIdx.x < S1_BLOCKS) ? partials[threadIdx.x] : 0;
  tmp[threadIdx.x] = v;
  __syncthreads();
  for (int off = 1; off < 512; off <<= 1) {
    int t = (threadIdx.x >= off) ? tmp[threadIdx.x - off] : 0;
    __syncthreads();
    tmp[threadIdx.x] += t;
    __syncthreads();
  }
  if (threadIdx.x < S1_BLOCKS) partials[threadIdx.x] = tmp[threadIdx.x] - v;
}

__global__ __launch_bounds__(1024) void scan_add(int* __restrict__ out,
                                                 const int* __restrict__ partials,
                                                 int* __restrict__ bucket_ptr,
                                                 int n_edges) {
  const int i = blockIdx.x * 1024 + threadIdx.x;
  if (i < SCAN_N) {
    const int v = out[i] + partials[blockIdx.x];
    out[i] = v;
    if ((i & (NCHUNK - 1)) == 0) bucket_ptr[i / NCHUNK] = v;
  }
  if (i == 0) bucket_ptr[NBUCK] = n_edges;
}

// ---------------------------------------------------------------------------
// Pass B: scatter packed (src | local<<17) into per-(bucket,chunk) regions.
// ---------------------------------------------------------------------------
__global__ __launch_bounds__(256) void passB_scatter(
    const int* __restrict__ src, const int* __restrict__ dst,
    const int* __restrict__ offs, unsigned* __restrict__ packed, int n_edges,
    int cepb) {
  __shared__ int cur[NBUCK];
  for (int i = threadIdx.x; i < NBUCK; i += 256)
    cur[i] = offs[i * NCHUNK + blockIdx.x];
  __syncthreads();
  const int s = blockIdx.x * cepb;
  const int e = min(n_edges, s + cepb);
  for (int i = s + threadIdx.x; i < e; i += 256) {
    const int d = dst[i];
    const int b = d >> 7;
    const int pos = atomicAdd(&cur[b], 1);
    packed[pos] = (unsigned)src[i] | ((unsigned)(d & (NPB - 1)) << 17);
  }
}

// ---------------------------------------------------------------------------
// Bucket sort: one block per bucket, LDS counting sort by local node,
// scatter back IN PLACE (value = src only). Emits node-level row_ptr.
// ---------------------------------------------------------------------------
__global__ __launch_bounds__(512) void bucket_sort(
    unsigned* __restrict__ packed, const int* __restrict__ bucket_ptr,
    int* __restrict__ row_ptr, int n_edges) {
  __shared__ unsigned stage[SORT_CAP];
  __shared__ int bins[NPB];
  __shared__ int scn[NPB];
  __shared__ int cur[NPB];
  const int b = blockIdx.x;
  const int s = bucket_ptr[b];
  const int cnt = bucket_ptr[b + 1] - s;
  const int tid = threadIdx.x;

  if (tid < NPB) bins[tid] = 0;
  __syncthreads();
  for (int i = tid; i < cnt; i += 512) {
    const unsigned pk = packed[s + i];
    stage[i] = pk;
    atomicAdd(&bins[pk >> 17], 1);
  }
  __syncthreads();
  if (tid < NPB) scn[tid] = bins[tid];
  __syncthreads();
  for (int off = 1; off < NPB; off <<= 1) {
    int t = (tid < NPB && tid >= off) ? scn[tid - off] : 0;
    __syncthreads();
    if (tid < NPB) scn[tid] += t;
    __syncthreads();
  }
  if (tid < NPB) {
    const int excl = scn[tid] - bins[tid];
    cur[tid] = excl;
    const int node = b * NPB + tid;
    if (node < N_NODES) row_ptr[node] = s + excl;
  }
  if (b == NBUCK - 1 && tid == 0) row_ptr[N_NODES] = n_edges;
  __syncthreads();
  for (int i = tid; i < cnt; i += 512) {
    const unsigned pk = stage[i];
    const int pos = atomicAdd(&cur[pk >> 17], 1);
    packed[s + pos] = pk & 0x1FFFFu;  // sorted; strip local bits
  }
}

// ---------------------------------------------------------------------------
// Fused SAGE layer, one block per 128-node bucket, 8 waves, 16 node-passes.
// Weights staged ONCE per block. Per pass each wave owns one node:
//   gather feat[adj[i]] quads -> shfl_xor butterfly -> per-wave LDS slot ->
//   in-wave GEMV: relu(mean@w_l + x@w_r + b).
// ---------------------------------------------------------------------------
template <int CH>
__global__ __launch_bounds__(512) void sage_block(
    const float* __restrict__ feat, const int* __restrict__ row_ptr,
    const int* __restrict__ adj, const float* __restrict__ w_l,
    const float* __restrict__ w_r, const float* __restrict__ b,
    float* __restrict__ out) {
  constexpr int Q = CH / 4;    // lanes per edge row
  constexpr int EPW = 64 / Q;  // edges per wave iteration
  __shared__ float wl[CH * HIDDEN];
  __shared__ float wr[CH * HIDDEN];
  __shared__ float bs[HIDDEN];
  __shared__ float mean_s[8][CH];
  __shared__ float xs[8][CH];

  const int tid = threadIdx.x;
  for (int i = tid; i < CH * HIDDEN; i += 512) {
    wl[i] = w_l[i];
    wr[i] = w_r[i];
  }
  if (tid < HIDDEN) bs[tid] = b[tid];
  __syncthreads();

  const int wave = tid >> 6;
  const int lane = tid & 63;
  const int base = blockIdx.x * NPB;
  const int q = lane & (Q - 1);
  const int esub = lane / Q;
  const int j = lane & 31;
  const int p = lane >> 5;

#pragma unroll 1
  for (int pass = 0; pass < NPB / 8; ++pass) {
    const int l = pass * 8 + wave;  // local node index in bucket
    const int n = base + l;
    if (n < N_NODES) {  // wave-uniform guard; no block barrier inside loop
      const int s = row_ptr[n];
      const int e = row_ptr[n + 1];

      float4 acc = {0.f, 0.f, 0.f, 0.f};
      for (int i = s + esub; i < e; i += EPW) {
        const float4 v = ((const float4*)(feat + (size_t)adj[i] * CH))[q];
        acc.x += v.x;
        acc.y += v.y;
        acc.z += v.z;
        acc.w += v.w;
      }
#pragma unroll
      for (int m = Q; m < 64; m <<= 1) {
        acc.x += __shfl_xor(acc.x, m, 64);
        acc.y += __shfl_xor(acc.y, m, 64);
        acc.z += __shfl_xor(acc.z, m, 64);
        acc.w += __shfl_xor(acc.w, m, 64);
      }
      const float inv = 1.0f / fmaxf((float)(e - s), 1.0f);
      if (esub == 0) {  // lane == q
        mean_s[wave][4 * q + 0] = acc.x * inv;
        mean_s[wave][4 * q + 1] = acc.y * inv;
        mean_s[wave][4 * q + 2] = acc.z * inv;
        mean_s[wave][4 * q + 3] = acc.w * inv;
        const float4 xv = ((const float4*)(feat + (size_t)n * CH))[q];
        xs[wave][4 * q + 0] = xv.x;
        xs[wave][4 * q + 1] = xv.y;
        xs[wave][4 * q + 2] = xv.z;
        xs[wave][4 * q + 3] = xv.w;
      }
      // intra-wave LDS RAW: in-order per-wave DS pipe; fence compiler only
      __builtin_amdgcn_wave_barrier();

      float o = 0.f;
#pragma unroll
      for (int k = p * (CH / 2); k < (p + 1) * (CH / 2); ++k)
        o = fmaf(mean_s[wave][k], wl[k * HIDDEN + j],
                 fmaf(xs[wave][k], wr[k * HIDDEN + j], o));
      o += __shfl_xor(o, 32, 64);
      if (p == 0) out[(size_t)n * HIDDEN + j] = fmaxf(o + bs[j], 0.f);
      __builtin_amdgcn_wave_barrier();
    }
  }
}

// ---------------------------------------------------------------------------
// FC head, register-tiled: out[N,1000] = h[N,32] @ fc_w[32,1000] + fc_b.
// 256 threads / 128-node tile. Each thread owns 4 columns (j = c*256+tid)
// with all 32 weights in VGPRs (128 regs). Node loop reads hs rows as
// float4 LDS broadcasts -> 16 fmaf per ds_read_b128 (VALU-bound, not DS).
// Stores coalesced (consecutive tid -> consecutive j).
// ---------------------------------------------------------------------------
#define FC_BN 128
__global__ __launch_bounds__(256) void fc_reg(
    const float* __restrict__ h, const float* __restrict__ fcw,
    const float* __restrict__ fcb, float* __restrict__ out) {
  __shared__ float hs[FC_BN * HIDDEN];
  const int tid = threadIdx.x;
  const int base = blockIdx.x * FC_BN;
  const int nvalid = min(FC_BN, N_NODES - base);

  // weights -> VGPRs (coalesced global reads), issued before hs staging sync
  float w[4][HIDDEN];
  float bias[4];
#pragma unroll
  for (int c = 0; c < 4; ++c) {
    const int j = c * 256 + tid;
    const bool valid = j < NUM_HH;
    bias[c] = valid ? fcb[j] : 0.f;
#pragma unroll
    for (int k = 0; k < HIDDEN; ++k)
      w[c][k] = valid ? fcw[k * NUM_HH + j] : 0.f;
  }

  const float4* s4 = (const float4*)(h + (size_t)base * HIDDEN);
  for (int i = tid; i < nvalid * (HIDDEN / 4); i += 256)
    ((float4*)hs)[i] = s4[i];
  __syncthreads();

#pragma unroll 2
  for (int n = 0; n < nvalid; ++n) {
    float a0 = bias[0], a1 = bias[1], a2 = bias[2], a3 = bias[3];
    const float4* hrow = (const float4*)(hs + n * HIDDEN);
#pragma unroll
    for (int k4 = 0; k4 < HIDDEN / 4; ++k4) {
      const float4 hv = hrow[k4];
      a0 = fmaf(hv.x, w[0][4 * k4 + 0], a0);
      a0 = fmaf(hv.y, w[0][4 * k4 + 1], a0);
      a0 = fmaf(hv.z, w[0][4 * k4 + 2], a0);
      a0 = fmaf(hv.w, w[0][4 * k4 + 3], a0);
      a1 = fmaf(hv.x, w[1][4 * k4 + 0], a1);
      a1 = fmaf(hv.y, w[1][4 * k4 + 1], a1);
      a1 = fmaf(hv.z, w[1][4 * k4 + 2], a1);
      a1 = fmaf(hv.w, w[1][4 * k4 + 3], a1);
      a2 = fmaf(hv.x, w[2][4 * k4 + 0], a2);
      a2 = fmaf(hv.y, w[2][4 * k4 + 1], a2);
      a2 = fmaf(hv.z, w[2][4 * k4 + 2], a2);
      a2 = fmaf(hv.w, w[2][4 * k4 + 3], a2);
      a3 = fmaf(hv.x, w[3][4 * k4 + 0], a3);
      a3 = fmaf(hv.y, w[3][4 * k4 + 1], a3);
      a3 = fmaf(hv.z, w[3][4 * k4 + 2], a3);
      a3 = fmaf(hv.w, w[3][4 * k4 + 3], a3);
    }
    float* orow = out + (size_t)(base + n) * NUM_HH;
    orow[tid] = a0;
    orow[256 + tid] = a1;
    orow[512 + tid] = a2;
    if (768 + tid < NUM_HH) orow[768 + tid] = a3;
  }
}

extern "C" void kernel_launch(void* const* d_in, const int* in_sizes, int n_in,
                              void* d_out, int out_size, void* d_ws,
                              size_t ws_size, hipStream_t stream) {
  const float* x = (const float*)d_in[0];
  const int* edge = (const int*)d_in[1];
  const float* w1_l = (const float*)d_in[2];
  const float* w1_r = (const float*)d_in[3];
  const float* b1 = (const float*)d_in[4];
  const float* w2_l = (const float*)d_in[5];
  const float* w2_r = (const float*)d_in[6];
  const float* b2 = (const float*)d_in[7];
  const float* fc_w = (const float*)d_in[8];
  const float* fc_b = (const float*)d_in[9];
  float* out = (float*)d_out;

  const int n_edges = in_sizes[1] / 2;
  const int* src = edge;
  const int* dst = edge + n_edges;

  // Workspace (~38.9 MB): packed/adj[E] | h1[N*32] | h2[N*32] | ptrs.
  // counts/offs (3.2 MB) alias the head of h2 (dead before sage2 writes h2).
  unsigned* packed = (unsigned*)d_ws;
  float* h1 = (float*)(packed + n_edges);
  float* h2 = h1 + (size_t)N_NODES * HIDDEN;
  int* counts = (int*)h2;       // alias, dead after scan_local
  int* offs = counts + SCAN_N;  // alias, dead after passB_scatter
  int* bucket_ptr = (int*)(h2 + (size_t)N_NODES * HIDDEN);
  int* partials = bucket_ptr + NBUCK + 1;
  int* row_ptr = partials + S1_BLOCKS + 1;

  const int cepb = (n_edges + NCHUNK - 1) / NCHUNK;
  const int fgrid = (N_NODES + FC_BN - 1) / FC_BN;

  // ---- bucket partition + node-level counting sort (shared by both layers)
  passA_count<<<NCHUNK, 256, 0, stream>>>(dst, counts, n_edges, cepb);
  scan_local<<<S1_BLOCKS, 1024, 0, stream>>>(counts, offs, partials);
  scan_partials<<<1, 512, 0, stream>>>(partials);
  scan_add<<<S1_BLOCKS, 1024, 0, stream>>>(offs, partials, bucket_ptr, n_edges);
  passB_scatter<<<NCHUNK, 256, 0, stream>>>(src, dst, offs, packed, n_edges,
                                            cepb);
  bucket_sort<<<NBUCK, 512, 0, stream>>>(packed, bucket_ptr, row_ptr, n_edges);

  // ---- Layer 1 (CH=16): x -> h1 ----
  sage_block<IN_CH><<<NBUCK, 512, 0, stream>>>(x, row_ptr, (const int*)packed,
                                               w1_l, w1_r, b1, h1);
  // ---- Layer 2 (CH=32): h1 -> h2 ----
  sage_block<HIDDEN><<<NBUCK, 512, 0, stream>>>(h1, row_ptr, (const int*)packed,
                                                w2_l, w2_r, b2, h2);
  // ---- FC head (register-tiled) ----
  fc_reg<<<fgrid, 256, 0, stream>>>(h2, fc_w, fc_b, out);
}

// Round 7
// 424.032 us; speedup vs baseline: 1.1503x; 1.1503x over previous
//
#include <hip/hip_runtime.h>

#define N_NODES 100000
#define IN_CH 16
#define HIDDEN 32
#define NUM_HH 1000

#define NPB 128                                   // nodes per bucket
#define NBUCK ((N_NODES + NPB - 1) / NPB)         // 782
#define NCHUNK 512                                // edge chunks (pass A/B blocks)
#define SCAN_N (NBUCK * NCHUNK)                   // 400384
#define S1_BLOCKS ((SCAN_N + 1023) / 1024)        // 391
#define SORT_CAP 6144  // bucket edges: mean 4096, sigma ~64 -> max ~4400 << cap

// ---------------------------------------------------------------------------
// Pass A: per-chunk bucket histogram (LDS), write counts[bucket][chunk].
// ---------------------------------------------------------------------------
__global__ __launch_bounds__(256) void passA_count(const int* __restrict__ dst,
                                                   int* __restrict__ counts,
                                                   int n_edges, int cepb) {
  __shared__ int hist[NBUCK];
  for (int i = threadIdx.x; i < NBUCK; i += 256) hist[i] = 0;
  __syncthreads();
  const int s = blockIdx.x * cepb;
  const int e = min(n_edges, s + cepb);
  for (int i = s + threadIdx.x; i < e; i += 256)
    atomicAdd(&hist[dst[i] >> 7], 1);
  __syncthreads();
  for (int i = threadIdx.x; i < NBUCK; i += 256)
    counts[i * NCHUNK + blockIdx.x] = hist[i];
}

// ---------------------------------------------------------------------------
// Exclusive scan over SCAN_N ints (bucket-major order).
// ---------------------------------------------------------------------------
__global__ __launch_bounds__(1024) void scan_local(const int* __restrict__ in,
                                                   int* __restrict__ out,
                                                   int* __restrict__ partials) {
  __shared__ int tmp[1024];
  const int i = blockIdx.x * 1024 + threadIdx.x;
  const int v = (i < SCAN_N) ? in[i] : 0;
  tmp[threadIdx.x] = v;
  __syncthreads();
  for (int off = 1; off < 1024; off <<= 1) {
    int t = (threadIdx.x >= off) ? tmp[threadIdx.x - off] : 0;
    __syncthreads();
    tmp[threadIdx.x] += t;
    __syncthreads();
  }
  if (i < SCAN_N) out[i] = tmp[threadIdx.x] - v;  // exclusive
  if (threadIdx.x == 1023) partials[blockIdx.x] = tmp[threadIdx.x];
}

__global__ __launch_bounds__(512) void scan_partials(int* __restrict__ partials) {
  __shared__ int tmp[512];
  const int v = (threadIdx.x < S1_BLOCKS) ? partials[threadIdx.x] : 0;
  tmp[threadIdx.x] = v;
  __syncthreads();
  for (int off = 1; off < 512; off <<= 1) {
    int t = (threadIdx.x >= off) ? tmp[threadIdx.x - off] : 0;
    __syncthreads();
    tmp[threadIdx.x] += t;
    __syncthreads();
  }
  if (threadIdx.x < S1_BLOCKS) partials[threadIdx.x] = tmp[threadIdx.x] - v;
}

__global__ __launch_bounds__(1024) void scan_add(int* __restrict__ out,
                                                 const int* __restrict__ partials,
                                                 int* __restrict__ bucket_ptr,
                                                 int n_edges) {
  const int i = blockIdx.x * 1024 + threadIdx.x;
  if (i < SCAN_N) {
    const int v = out[i] + partials[blockIdx.x];
    out[i] = v;
    if ((i & (NCHUNK - 1)) == 0) bucket_ptr[i / NCHUNK] = v;
  }
  if (i == 0) bucket_ptr[NBUCK] = n_edges;
}

// ---------------------------------------------------------------------------
// Pass B: scatter packed (src | local<<17) into per-(bucket,chunk) regions.
// ---------------------------------------------------------------------------
__global__ __launch_bounds__(256) void passB_scatter(
    const int* __restrict__ src, const int* __restrict__ dst,
    const int* __restrict__ offs, unsigned* __restrict__ packed, int n_edges,
    int cepb) {
  __shared__ int cur[NBUCK];
  for (int i = threadIdx.x; i < NBUCK; i += 256)
    cur[i] = offs[i * NCHUNK + blockIdx.x];
  __syncthreads();
  const int s = blockIdx.x * cepb;
  const int e = min(n_edges, s + cepb);
  for (int i = s + threadIdx.x; i < e; i += 256) {
    const int d = dst[i];
    const int b = d >> 7;
    const int pos = atomicAdd(&cur[b], 1);
    packed[pos] = (unsigned)src[i] | ((unsigned)(d & (NPB - 1)) << 17);
  }
}

// ---------------------------------------------------------------------------
// Bucket sort: one block per bucket, LDS counting sort by local node,
// scatter back IN PLACE (value = src only). Emits node-level row_ptr.
// ---------------------------------------------------------------------------
__global__ __launch_bounds__(512) void bucket_sort(
    unsigned* __restrict__ packed, const int* __restrict__ bucket_ptr,
    int* __restrict__ row_ptr, int n_edges) {
  __shared__ unsigned stage[SORT_CAP];
  __shared__ int bins[NPB];
  __shared__ int scn[NPB];
  __shared__ int cur[NPB];
  const int b = blockIdx.x;
  const int s = bucket_ptr[b];
  const int cnt = bucket_ptr[b + 1] - s;
  const int tid = threadIdx.x;

  if (tid < NPB) bins[tid] = 0;
  __syncthreads();
  for (int i = tid; i < cnt; i += 512) {
    const unsigned pk = packed[s + i];
    stage[i] = pk;
    atomicAdd(&bins[pk >> 17], 1);
  }
  __syncthreads();
  if (tid < NPB) scn[tid] = bins[tid];
  __syncthreads();
  for (int off = 1; off < NPB; off <<= 1) {
    int t = (tid < NPB && tid >= off) ? scn[tid - off] : 0;
    __syncthreads();
    if (tid < NPB) scn[tid] += t;
    __syncthreads();
  }
  if (tid < NPB) {
    const int excl = scn[tid] - bins[tid];
    cur[tid] = excl;
    const int node = b * NPB + tid;
    if (node < N_NODES) row_ptr[node] = s + excl;
  }
  if (b == NBUCK - 1 && tid == 0) row_ptr[N_NODES] = n_edges;
  __syncthreads();
  for (int i = tid; i < cnt; i += 512) {
    const unsigned pk = stage[i];
    const int pos = atomicAdd(&cur[pk >> 17], 1);
    packed[s + pos] = pk & 0x1FFFFu;  // sorted; strip local bits
  }
}

// ---------------------------------------------------------------------------
// Fused SAGE layer, one block per 128-node bucket, 8 waves, 16 node-passes.
// Bucket adjacency staged in LDS once (coalesced) -> gather loop reads adj
// via ds_read (short dep chain), node's own x-row load hoisted ahead of the
// gather so its latency hides. Weights staged once per block. Per pass each
// wave owns one node: gather feat[adj] quads -> shfl_xor butterfly ->
// in-wave GEMV: relu(mean@w_l + x@w_r + b).
// ---------------------------------------------------------------------------
template <int CH>
__global__ __launch_bounds__(512) void sage_block(
    const float* __restrict__ feat, const int* __restrict__ row_ptr,
    const unsigned* __restrict__ adj, const int* __restrict__ bucket_ptr,
    const float* __restrict__ w_l, const float* __restrict__ w_r,
    const float* __restrict__ b, float* __restrict__ out) {
  constexpr int Q = CH / 4;    // lanes per edge row
  constexpr int EPW = 64 / Q;  // edges per wave iteration
  __shared__ unsigned s_adj[SORT_CAP];
  __shared__ float wl[CH * HIDDEN];
  __shared__ float wr[CH * HIDDEN];
  __shared__ float bs[HIDDEN];
  __shared__ float mean_s[8][CH];
  __shared__ float xs[8][CH];

  const int tid = threadIdx.x;
  const int bk = blockIdx.x;
  const int base = bk * NPB;
  const int bstart = bucket_ptr[bk];
  const int bcnt = bucket_ptr[bk + 1] - bstart;

  for (int i = tid; i < CH * HIDDEN; i += 512) {
    wl[i] = w_l[i];
    wr[i] = w_r[i];
  }
  if (tid < HIDDEN) bs[tid] = b[tid];
  for (int i = tid; i < bcnt; i += 512) s_adj[i] = adj[bstart + i];
  __syncthreads();

  const int wave = tid >> 6;
  const int lane = tid & 63;
  const int q = lane & (Q - 1);
  const int esub = lane / Q;
  const int j = lane & 31;
  const int p = lane >> 5;

#pragma unroll 1
  for (int pass = 0; pass < NPB / 8; ++pass) {
    const int l = pass * 8 + wave;  // local node index in bucket
    const int n = base + l;
    if (n < N_NODES) {  // wave-uniform guard; no block barrier inside loop
      const int s = row_ptr[n] - bstart;
      const int e = row_ptr[n + 1] - bstart;

      // hoist own-feature load: latency hides under the gather loop
      float4 xv = {0.f, 0.f, 0.f, 0.f};
      if (esub == 0) xv = ((const float4*)(feat + (size_t)n * CH))[q];

      float4 acc = {0.f, 0.f, 0.f, 0.f};
      for (int i = s + esub; i < e; i += EPW) {
        const int sn = (int)s_adj[i];
        const float4 v = ((const float4*)(feat + (size_t)sn * CH))[q];
        acc.x += v.x;
        acc.y += v.y;
        acc.z += v.z;
        acc.w += v.w;
      }
#pragma unroll
      for (int m = Q; m < 64; m <<= 1) {
        acc.x += __shfl_xor(acc.x, m, 64);
        acc.y += __shfl_xor(acc.y, m, 64);
        acc.z += __shfl_xor(acc.z, m, 64);
        acc.w += __shfl_xor(acc.w, m, 64);
      }
      const float inv = 1.0f / fmaxf((float)(e - s), 1.0f);
      if (esub == 0) {  // lane == q
        mean_s[wave][4 * q + 0] = acc.x * inv;
        mean_s[wave][4 * q + 1] = acc.y * inv;
        mean_s[wave][4 * q + 2] = acc.z * inv;
        mean_s[wave][4 * q + 3] = acc.w * inv;
        xs[wave][4 * q + 0] = xv.x;
        xs[wave][4 * q + 1] = xv.y;
        xs[wave][4 * q + 2] = xv.z;
        xs[wave][4 * q + 3] = xv.w;
      }
      // intra-wave LDS RAW: in-order per-wave DS pipe; fence compiler only
      __builtin_amdgcn_wave_barrier();

      float o = 0.f;
#pragma unroll
      for (int k = p * (CH / 2); k < (p + 1) * (CH / 2); ++k)
        o = fmaf(mean_s[wave][k], wl[k * HIDDEN + j],
                 fmaf(xs[wave][k], wr[k * HIDDEN + j], o));
      o += __shfl_xor(o, 32, 64);
      if (p == 0) out[(size_t)n * HIDDEN + j] = fmaxf(o + bs[j], 0.f);
      __builtin_amdgcn_wave_barrier();
    }
  }
}

// ---------------------------------------------------------------------------
// FC head, LDS-free: out[N,1000] = h[N,32] @ fc_w[32,1000] + fc_b.
// 256 threads / 128-node tile; each thread owns 4 columns with all 32
// weights in VGPRs. h rows are read directly from global with a
// WAVE-UNIFORM address -> one 16B broadcast load per instruction (L1-
// resident 16 KB tile), zero DS traffic. Stores coalesced across tid.
// ---------------------------------------------------------------------------
#define FC_BN 128
__global__ __launch_bounds__(256) void fc_direct(
    const float* __restrict__ h, const float* __restrict__ fcw,
    const float* __restrict__ fcb, float* __restrict__ out) {
  const int tid = threadIdx.x;
  const int base = blockIdx.x * FC_BN;
  const int nvalid = min(FC_BN, N_NODES - base);

  float w[4][HIDDEN];
  float bias[4];
#pragma unroll
  for (int c = 0; c < 4; ++c) {
    const int j = c * 256 + tid;
    const bool valid = j < NUM_HH;
    bias[c] = valid ? fcb[j] : 0.f;
#pragma unroll
    for (int k = 0; k < HIDDEN; ++k)
      w[c][k] = valid ? fcw[k * NUM_HH + j] : 0.f;
  }

#pragma unroll 2
  for (int n = 0; n < nvalid; ++n) {
    const float4* hrow = (const float4*)(h + (size_t)(base + n) * HIDDEN);
    float a0 = bias[0], a1 = bias[1], a2 = bias[2], a3 = bias[3];
#pragma unroll
    for (int k4 = 0; k4 < HIDDEN / 4; ++k4) {
      const float4 hv = hrow[k4];
      a0 = fmaf(hv.x, w[0][4 * k4 + 0], a0);
      a0 = fmaf(hv.y, w[0][4 * k4 + 1], a0);
      a0 = fmaf(hv.z, w[0][4 * k4 + 2], a0);
      a0 = fmaf(hv.w, w[0][4 * k4 + 3], a0);
      a1 = fmaf(hv.x, w[1][4 * k4 + 0], a1);
      a1 = fmaf(hv.y, w[1][4 * k4 + 1], a1);
      a1 = fmaf(hv.z, w[1][4 * k4 + 2], a1);
      a1 = fmaf(hv.w, w[1][4 * k4 + 3], a1);
      a2 = fmaf(hv.x, w[2][4 * k4 + 0], a2);
      a2 = fmaf(hv.y, w[2][4 * k4 + 1], a2);
      a2 = fmaf(hv.z, w[2][4 * k4 + 2], a2);
      a2 = fmaf(hv.w, w[2][4 * k4 + 3], a2);
      a3 = fmaf(hv.x, w[3][4 * k4 + 0], a3);
      a3 = fmaf(hv.y, w[3][4 * k4 + 1], a3);
      a3 = fmaf(hv.z, w[3][4 * k4 + 2], a3);
      a3 = fmaf(hv.w, w[3][4 * k4 + 3], a3);
    }
    float* orow = out + (size_t)(base + n) * NUM_HH;
    orow[tid] = a0;
    orow[256 + tid] = a1;
    orow[512 + tid] = a2;
    if (768 + tid < NUM_HH) orow[768 + tid] = a3;
  }
}

extern "C" void kernel_launch(void* const* d_in, const int* in_sizes, int n_in,
                              void* d_out, int out_size, void* d_ws,
                              size_t ws_size, hipStream_t stream) {
  const float* x = (const float*)d_in[0];
  const int* edge = (const int*)d_in[1];
  const float* w1_l = (const float*)d_in[2];
  const float* w1_r = (const float*)d_in[3];
  const float* b1 = (const float*)d_in[4];
  const float* w2_l = (const float*)d_in[5];
  const float* w2_r = (const float*)d_in[6];
  const float* b2 = (const float*)d_in[7];
  const float* fc_w = (const float*)d_in[8];
  const float* fc_b = (const float*)d_in[9];
  float* out = (float*)d_out;

  const int n_edges = in_sizes[1] / 2;
  const int* src = edge;
  const int* dst = edge + n_edges;

  // Workspace (~38.9 MB): packed/adj[E] | h1[N*32] | h2[N*32] | ptrs.
  // counts/offs (3.2 MB) alias the head of h2 (dead before sage2 writes h2).
  unsigned* packed = (unsigned*)d_ws;
  float* h1 = (float*)(packed + n_edges);
  float* h2 = h1 + (size_t)N_NODES * HIDDEN;
  int* counts = (int*)h2;       // alias, dead after scan_local
  int* offs = counts + SCAN_N;  // alias, dead after passB_scatter
  int* bucket_ptr = (int*)(h2 + (size_t)N_NODES * HIDDEN);
  int* partials = bucket_ptr + NBUCK + 1;
  int* row_ptr = partials + S1_BLOCKS + 1;

  const int cepb = (n_edges + NCHUNK - 1) / NCHUNK;
  const int fgrid = (N_NODES + FC_BN - 1) / FC_BN;

  // ---- bucket partition + node-level counting sort (shared by both layers)
  passA_count<<<NCHUNK, 256, 0, stream>>>(dst, counts, n_edges, cepb);
  scan_local<<<S1_BLOCKS, 1024, 0, stream>>>(counts, offs, partials);
  scan_partials<<<1, 512, 0, stream>>>(partials);
  scan_add<<<S1_BLOCKS, 1024, 0, stream>>>(offs, partials, bucket_ptr, n_edges);
  passB_scatter<<<NCHUNK, 256, 0, stream>>>(src, dst, offs, packed, n_edges,
                                            cepb);
  bucket_sort<<<NBUCK, 512, 0, stream>>>(packed, bucket_ptr, row_ptr, n_edges);

  // ---- Layer 1 (CH=16): x -> h1 ----
  sage_block<IN_CH><<<NBUCK, 512, 0, stream>>>(x, row_ptr, packed, bucket_ptr,
                                               w1_l, w1_r, b1, h1);
  // ---- Layer 2 (CH=32): h1 -> h2 ----
  sage_block<HIDDEN><<<NBUCK, 512, 0, stream>>>(h1, row_ptr, packed, bucket_ptr,
                                                w2_l, w2_r, b2, h2);
  // ---- FC head (LDS-free, uniform broadcast reads) ----
  fc_direct<<<fgrid, 256, 0, stream>>>(h2, fc_w, fc_b, out);
}